// Round 5
// baseline (53.725 us; speedup 1.0000x reference)
//
#include <hip/hip_runtime.h>

#define B_   2
#define H_   16
#define S_   2048
#define D_   64
#define BQ   128    // q rows per block (16 per wave, 8 waves)
#define BK   64
#define NW   8
// fold 1/sqrt(64) * log2(e) into Q so softmax works in exp2 domain
#define QSCALE 0.18033688011112042f
#define DEFER_THR 8.0f

typedef _Float16 f16x8 __attribute__((ext_vector_type(8)));
typedef _Float16 f16x4 __attribute__((ext_vector_type(4)));
typedef float    f32x4 __attribute__((ext_vector_type(4)));

typedef const unsigned int __attribute__((address_space(1))) gu32;
typedef unsigned int       __attribute__((address_space(3))) lu32;

#define KBYTES_PER_HEAD (S_ * 128)                       // 256 KB f16 per head per tensor
#define WS_V_OFF ((size_t)B_ * H_ * KBYTES_PER_HEAD)     // 8.4 MB
#define WS_NEED  (2 * WS_V_OFF)

// ---------------- fused prepass: K -> swizzled f16 tiles, V -> transposed swizzled f16 tiles
// K tile image: element (row,d) at byte  row*128 + (((d>>3) ^ (row&7))<<4) + (d&7)*2
// V tile image: element (d,k)  at byte  d*128   + (((k>>3) ^ (d&7))<<4)   + (k&7)*2
__global__ __launch_bounds__(256) void prep_kv(const float* __restrict__ K,
                                               const float* __restrict__ V,
                                               char* __restrict__ ws)
{
    if (blockIdx.x < (B_ * H_ * S_ * 8) / 256) {
        const int gidx = blockIdx.x * 256 + threadIdx.x;
        const int gcol = gidx & 7;
        const int srow = gidx >> 3;                      // bh*S + s
        const float4* src = (const float4*)(K + (size_t)srow * D_ + gcol * 8);
        float4 a = src[0], b = src[1];
        f16x8 h;
        h[0] = (_Float16)a.x; h[1] = (_Float16)a.y; h[2] = (_Float16)a.z; h[3] = (_Float16)a.w;
        h[4] = (_Float16)b.x; h[5] = (_Float16)b.y; h[6] = (_Float16)b.z; h[7] = (_Float16)b.w;
        const int s  = srow & (S_ - 1);
        const int bh = srow >> 11;
        size_t off = (size_t)bh * KBYTES_PER_HEAD + (size_t)(s >> 6) * 8192
                   + (s & 63) * 128 + ((gcol ^ (s & 7)) << 4);
        *(f16x8*)(ws + off) = h;
    } else {
        __shared__ _Float16 Vl[64][72];
        const int tile = blockIdx.x - (B_ * H_ * S_ * 8) / 256;  // bh*32 + t
        const int bh = tile >> 5, t = tile & 31;
        const float* vb = V + ((size_t)bh * S_ + t * 64) * D_;
        const int tid = threadIdx.x;
        #pragma unroll
        for (int it = 0; it < 2; ++it) {
            const int row = (tid >> 3) + it * 32;
            const int c8  = (tid & 7) * 8;
            const float4* p = (const float4*)(vb + row * D_ + c8);
            float4 a = p[0], b = p[1];
            f16x8 h;
            h[0] = (_Float16)a.x; h[1] = (_Float16)a.y; h[2] = (_Float16)a.z; h[3] = (_Float16)a.w;
            h[4] = (_Float16)b.x; h[5] = (_Float16)b.y; h[6] = (_Float16)b.z; h[7] = (_Float16)b.w;
            *(f16x8*)&Vl[row][c8] = h;
        }
        __syncthreads();
        char* out = ws + WS_V_OFF + (size_t)bh * KBYTES_PER_HEAD + t * 8192;
        #pragma unroll
        for (int it = 0; it < 2; ++it) {
            const int task = tid + it * 256;
            const int d = task >> 3, kg = task & 7;
            f16x8 h;
            #pragma unroll
            for (int j = 0; j < 8; ++j) h[j] = Vl[kg * 8 + j][d];
            *(f16x8*)(out + d * 128 + ((kg ^ (d & 7)) << 4)) = h;
        }
    }
}

// ---------------- main attention kernel
template<bool MASK>
__device__ __forceinline__ void compute_tile(
    const _Float16* __restrict__ SMb, _Float16 (*__restrict__ Plw)[72],
    const f16x8 aq[2], f32x4 accO[4], float& m_r, float& l_r,
    int g, int l15, int sx, int dq)
{
    const _Float16* Kb = SMb;
    const _Float16* Vb = SMb + 4096;

    // QK^T swapped: A = K rows, B = Q  ->  C[k = sub*16+g*4+r][q = l15]
    f32x4 accS[4];
    #pragma unroll
    for (int s = 0; s < 4; ++s) accS[s] = (f32x4){0.f, 0.f, 0.f, 0.f};
    __builtin_amdgcn_s_setprio(1);
    #pragma unroll
    for (int sub = 0; sub < 4; ++sub) {
        if (MASK && (sub * 16 > dq + 15)) continue;      // wave-uniform fully-masked sub
        #pragma unroll
        for (int kc = 0; kc < 2; ++kc) {
            f16x8 ak = *(const f16x8*)(Kb + ((sub * 16 + l15) * 64 + (((kc * 4 + g) ^ sx) << 3)));
            accS[sub] = __builtin_amdgcn_mfma_f32_16x16x32_f16(ak, aq[kc], accS[sub], 0, 0, 0);
        }
    }
    __builtin_amdgcn_s_setprio(0);

    // masked scores + per-lane local max (this lane's 16 k-values for q = l15)
    float ps[4][4];
    float pmax = -1e30f;
    #pragma unroll
    for (int sub = 0; sub < 4; ++sub) {
        const bool fullmask = MASK && (sub * 16 > dq + 15);
        const bool diag     = MASK && !fullmask && (sub * 16 + 15 > dq);
        #pragma unroll
        for (int r = 0; r < 4; ++r) {
            float s = fullmask ? -1e30f : accS[sub][r];
            if (diag && (sub * 16 + g * 4 + r > dq + l15)) s = -1e30f;
            ps[sub][r] = s;
            pmax = fmaxf(pmax, s);
        }
    }

    // defer-max (T13): rescale only when some lane's local max outgrows m_r + THR.
    // Branch is wave-uniform (ballot). Common case: no cross-lane ops at all.
    if (!__all(pmax <= m_r + DEFER_THR)) {
        float mx = pmax;
        mx = fmaxf(mx, __shfl_xor(mx, 16));
        mx = fmaxf(mx, __shfl_xor(mx, 32));
        const float mnew  = fmaxf(m_r, mx);               // row-uniform
        const float alpha = __builtin_amdgcn_exp2f(m_r - mnew);
        l_r *= alpha;
        #pragma unroll
        for (int d = 0; d < 4; ++d)
            #pragma unroll
            for (int r = 0; r < 4; ++r) accO[d][r] *= alpha;
        m_r = mnew;
    }

    // exp2 with (possibly stale-by-<=THR) m_r: values bounded by 2^THR = 256, f16-safe.
    #pragma unroll
    for (int sub = 0; sub < 4; ++sub)
        #pragma unroll
        for (int r = 0; r < 4; ++r)
            ps[sub][r] = __builtin_amdgcn_exp2f(ps[sub][r] - m_r);

    // P -> LDS relayout first (get ds_writes in flight early): row q=l15, col k
    #pragma unroll
    for (int sub = 0; sub < 4; ++sub) {
        f16x4 q4;
        q4[0] = (_Float16)ps[sub][0]; q4[1] = (_Float16)ps[sub][1];
        q4[2] = (_Float16)ps[sub][2]; q4[3] = (_Float16)ps[sub][3];
        *(f16x4*)&Plw[l15][sub * 16 + g * 4] = q4;
    }

    // per-lane partial row-sum; cross-lane reduce deferred to epilogue
    float rs = 0.f;
    #pragma unroll
    for (int sub = 0; sub < 4; ++sub)
        #pragma unroll
        for (int r = 0; r < 4; ++r) rs += ps[sub][r];
    l_r += rs;

    asm volatile("s_waitcnt lgkmcnt(0)" ::: "memory");
    __builtin_amdgcn_sched_barrier(0);

    f16x8 pb[2];
    pb[0] = *(const f16x8*)&Plw[l15][g * 8];
    pb[1] = *(const f16x8*)&Plw[l15][32 + g * 8];

    // PV swapped: A = V^T rows (d), B = P^T cols (q) -> accO[dsub]: d = dsub*16+g*4+r, q = l15
    __builtin_amdgcn_s_setprio(1);
    #pragma unroll
    for (int d = 0; d < 4; ++d)
        #pragma unroll
        for (int kc = 0; kc < 2; ++kc) {
            f16x8 av = *(const f16x8*)(Vb + ((d * 16 + l15) * 64 + (((kc * 4 + g) ^ sx) << 3)));
            accO[d] = __builtin_amdgcn_mfma_f32_16x16x32_f16(av, pb[kc], accO[d], 0, 0, 0);
        }
    __builtin_amdgcn_s_setprio(0);
}

__global__ __launch_bounds__(512, 4) void attn_main(
    const float* __restrict__ Q, const char* __restrict__ ws, float* __restrict__ O)
{
    __shared__ _Float16 SM[2][8192];        // [buf][ K tile 0..4095 | V tile 4096..8191 ]
    __shared__ _Float16 Pl[NW][16][72];

    const int tid  = threadIdx.x;
    const int lane = tid & 63;
    const int w    = tid >> 6;              // wave 0..7
    const int g    = lane >> 4;
    const int l15  = lane & 15;
    const int sx   = l15 & 7;

    // 1-D grid: id = bh + 32*qi  ->  id%8 = bh%8 (head -> XCD affinity, K/V L2-resident);
    // qt reversed so heaviest blocks dispatch first.
    const int id    = blockIdx.x;
    const int bh    = id & 31;
    const int qt    = (S_ / BQ - 1) - (id >> 5);
    const int qbase = qt * BQ;

    const char* kbase = ws + (size_t)bh * KBYTES_PER_HEAD;
    const char* vbase = ws + WS_V_OFF + (size_t)bh * KBYTES_PER_HEAD;

    // hoist Q fragments, pre-scaled into exp2 domain
    f16x8 aq[2];
    {
        const float* qrow = Q + ((size_t)bh * S_ + qbase + w * 16 + l15) * D_;
        #pragma unroll
        for (int kc = 0; kc < 2; ++kc) {
            const float4* p = (const float4*)(qrow + kc * 32 + g * 8);
            float4 x0 = p[0], x1 = p[1];
            f16x8 h;
            h[0] = (_Float16)(x0.x * QSCALE); h[1] = (_Float16)(x0.y * QSCALE);
            h[2] = (_Float16)(x0.z * QSCALE); h[3] = (_Float16)(x0.w * QSCALE);
            h[4] = (_Float16)(x1.x * QSCALE); h[5] = (_Float16)(x1.y * QSCALE);
            h[6] = (_Float16)(x1.z * QSCALE); h[7] = (_Float16)(x1.w * QSCALE);
            aq[kc] = h;
        }
    }

    f32x4 accO[4];
    #pragma unroll
    for (int i = 0; i < 4; ++i) accO[i] = (f32x4){0.f, 0.f, 0.f, 0.f};
    float m_r = -1e30f, l_r = 0.f;

    const int nt = 2 * qt + 2;              // tiles; last two straddle the diagonal
    const int dqw = qbase + w * 16;         // wave q-row base

    // stage tile t: 16 x 1KB chunks, 2 per wave, linear LDS dest (pre-swizzled source)
    auto STAGE = [&](int t, int buf) {
        #pragma unroll
        for (int i = 0; i < 2; ++i) {
            const int c = w * 2 + i;
            const char* src = (c < 8 ? kbase + (size_t)t * 8192 + c * 1024
                                     : vbase + (size_t)t * 8192 + (c - 8) * 1024) + lane * 16;
            __builtin_amdgcn_global_load_lds((gu32*)src, (lu32*)&SM[buf][c * 512], 16, 0, 0);
        }
    };

    STAGE(0, 0);
    for (int t = 0; t < nt - 2; ++t) {      // fully-visible tiles
        STAGE(t + 1, (t + 1) & 1);
        asm volatile("s_waitcnt vmcnt(2)" ::: "memory");
        __builtin_amdgcn_s_barrier();
        compute_tile<false>(&SM[t & 1][0], Pl[w], aq, accO, m_r, l_r, g, l15, sx, 0);
        __builtin_amdgcn_s_barrier();
    }
    // t = nt-2 (diagonal for waves 0-3)
    STAGE(nt - 1, (nt - 1) & 1);
    asm volatile("s_waitcnt vmcnt(2)" ::: "memory");
    __builtin_amdgcn_s_barrier();
    compute_tile<true>(&SM[(nt - 2) & 1][0], Pl[w], aq, accO, m_r, l_r, g, l15, sx,
                       dqw - (nt - 2) * 64);
    __builtin_amdgcn_s_barrier();
    // t = nt-1 (diagonal for waves 4-7; fully masked for 0-3)
    asm volatile("s_waitcnt vmcnt(0)" ::: "memory");
    __builtin_amdgcn_s_barrier();
    compute_tile<true>(&SM[(nt - 1) & 1][0], Pl[w], aq, accO, m_r, l_r, g, l15, sx,
                       dqw - (nt - 1) * 64);

    // epilogue: complete the deferred row-sum reduce (once per kernel, not per tile)
    float l = l_r;
    l += __shfl_xor(l, 16);
    l += __shfl_xor(l, 32);
    const float inv = 1.0f / l;
    float* orow = O + ((size_t)bh * S_ + qbase + w * 16 + l15) * D_;
    #pragma unroll
    for (int d = 0; d < 4; ++d) {
        f32x4 o = accO[d] * inv;
        *(f32x4*)&orow[d * 16 + g * 4] = o;
    }
}

extern "C" void kernel_launch(void* const* d_in, const int* in_sizes, int n_in,
                              void* d_out, int out_size, void* d_ws, size_t ws_size,
                              hipStream_t stream) {
    const float* q = (const float*)d_in[0];
    const float* k = (const float*)d_in[1];
    const float* v = (const float*)d_in[2];
    // d_in[3] (mask) intentionally never read — causality computed in-kernel
    float* o = (float*)d_out;
    char* ws = (char*)d_ws;

    if (ws_size < WS_NEED) return;

    const int kblocks = (B_ * H_ * S_ * 8) / 256;        // 1024
    const int vblocks = B_ * H_ * (S_ / 64);             // 1024
    prep_kv<<<kblocks + vblocks, 256, 0, stream>>>(k, v, ws);
    attn_main<<<(S_ / BQ) * B_ * H_, 512, 0, stream>>>(q, ws, o);
}

// Round 6
// 53.686 us; speedup vs baseline: 1.0007x; 1.0007x over previous
//
#include <hip/hip_runtime.h>

#define B_   2
#define H_   16
#define S_   2048
#define D_   64
#define BQ   128    // q rows per block (16 per wave, 8 waves)
#define BK   64
#define NW   8
// fold 1/sqrt(64) * log2(e) into Q so softmax works in exp2 domain
#define QSCALE 0.18033688011112042f
#define DEFER_THR 8.0f

typedef _Float16 f16x8 __attribute__((ext_vector_type(8)));
typedef _Float16 f16x4 __attribute__((ext_vector_type(4)));
typedef float    f32x4 __attribute__((ext_vector_type(4)));

typedef const unsigned int __attribute__((address_space(1))) gu32;
typedef unsigned int       __attribute__((address_space(3))) lu32;

#define KBYTES_PER_HEAD (S_ * 128)                       // 256 KB f16 per head per tensor
#define WS_V_OFF ((size_t)B_ * H_ * KBYTES_PER_HEAD)     // 8.4 MB
#define WS_NEED  (2 * WS_V_OFF)

// ---------------- fused prepass: K -> swizzled f16 tiles, V -> transposed swizzled f16 tiles
// K tile image: element (row,d) at byte  row*128 + (((d>>3) ^ (row&7))<<4) + (d&7)*2
// V tile image: element (d,k)  at byte  d*128   + (((k>>3) ^ (d&7))<<4)   + (k&7)*2
__global__ __launch_bounds__(256) void prep_kv(const float* __restrict__ K,
                                               const float* __restrict__ V,
                                               char* __restrict__ ws)
{
    if (blockIdx.x < (B_ * H_ * S_ * 8) / 256) {
        const int gidx = blockIdx.x * 256 + threadIdx.x;
        const int gcol = gidx & 7;
        const int srow = gidx >> 3;                      // bh*S + s
        const float4* src = (const float4*)(K + (size_t)srow * D_ + gcol * 8);
        float4 a = src[0], b = src[1];
        f16x8 h;
        h[0] = (_Float16)a.x; h[1] = (_Float16)a.y; h[2] = (_Float16)a.z; h[3] = (_Float16)a.w;
        h[4] = (_Float16)b.x; h[5] = (_Float16)b.y; h[6] = (_Float16)b.z; h[7] = (_Float16)b.w;
        const int s  = srow & (S_ - 1);
        const int bh = srow >> 11;
        size_t off = (size_t)bh * KBYTES_PER_HEAD + (size_t)(s >> 6) * 8192
                   + (s & 63) * 128 + ((gcol ^ (s & 7)) << 4);
        *(f16x8*)(ws + off) = h;
    } else {
        __shared__ _Float16 Vl[64][72];
        const int tile = blockIdx.x - (B_ * H_ * S_ * 8) / 256;  // bh*32 + t
        const int bh = tile >> 5, t = tile & 31;
        const float* vb = V + ((size_t)bh * S_ + t * 64) * D_;
        const int tid = threadIdx.x;
        #pragma unroll
        for (int it = 0; it < 2; ++it) {
            const int row = (tid >> 3) + it * 32;
            const int c8  = (tid & 7) * 8;
            const float4* p = (const float4*)(vb + row * D_ + c8);
            float4 a = p[0], b = p[1];
            f16x8 h;
            h[0] = (_Float16)a.x; h[1] = (_Float16)a.y; h[2] = (_Float16)a.z; h[3] = (_Float16)a.w;
            h[4] = (_Float16)b.x; h[5] = (_Float16)b.y; h[6] = (_Float16)b.z; h[7] = (_Float16)b.w;
            *(f16x8*)&Vl[row][c8] = h;
        }
        __syncthreads();
        char* out = ws + WS_V_OFF + (size_t)bh * KBYTES_PER_HEAD + t * 8192;
        #pragma unroll
        for (int it = 0; it < 2; ++it) {
            const int task = tid + it * 256;
            const int d = task >> 3, kg = task & 7;
            f16x8 h;
            #pragma unroll
            for (int j = 0; j < 8; ++j) h[j] = Vl[kg * 8 + j][d];
            *(f16x8*)(out + d * 128 + ((kg ^ (d & 7)) << 4)) = h;
        }
    }
}

// ---------------- main attention kernel
template<bool MASK>
__device__ __forceinline__ void compute_tile(
    const _Float16* __restrict__ SMb, _Float16 (*__restrict__ Plw)[72],
    const f16x8 aq[2], f32x4 accO[4], float& m_r, float& l_r,
    int g, int l15, int sx, int dq)
{
    const _Float16* Kb = SMb;
    const _Float16* Vb = SMb + 4096;

    // QK^T swapped: A = K rows, B = Q  ->  C[k = sub*16+g*4+r][q = l15]
    f32x4 accS[4];
    #pragma unroll
    for (int s = 0; s < 4; ++s) accS[s] = (f32x4){0.f, 0.f, 0.f, 0.f};
    __builtin_amdgcn_s_setprio(1);
    #pragma unroll
    for (int sub = 0; sub < 4; ++sub) {
        if (MASK && (sub * 16 > dq + 15)) continue;      // wave-uniform fully-masked sub
        #pragma unroll
        for (int kc = 0; kc < 2; ++kc) {
            f16x8 ak = *(const f16x8*)(Kb + ((sub * 16 + l15) * 64 + (((kc * 4 + g) ^ sx) << 3)));
            accS[sub] = __builtin_amdgcn_mfma_f32_16x16x32_f16(ak, aq[kc], accS[sub], 0, 0, 0);
        }
    }
    __builtin_amdgcn_s_setprio(0);

    // masked scores + per-lane local max (this lane's 16 k-values for q = l15)
    float ps[4][4];
    float pmax = -1e30f;
    #pragma unroll
    for (int sub = 0; sub < 4; ++sub) {
        const bool fullmask = MASK && (sub * 16 > dq + 15);
        const bool diag     = MASK && !fullmask && (sub * 16 + 15 > dq);
        #pragma unroll
        for (int r = 0; r < 4; ++r) {
            float s = fullmask ? -1e30f : accS[sub][r];
            if (diag && (sub * 16 + g * 4 + r > dq + l15)) s = -1e30f;
            ps[sub][r] = s;
            pmax = fmaxf(pmax, s);
        }
    }

    // defer-max (T13): rescale only when some lane's local max outgrows m_r + THR.
    // Branch is wave-uniform (ballot). Common case: no cross-lane ops at all.
    if (!__all(pmax <= m_r + DEFER_THR)) {
        float mx = pmax;
        mx = fmaxf(mx, __shfl_xor(mx, 16));
        mx = fmaxf(mx, __shfl_xor(mx, 32));
        const float mnew  = fmaxf(m_r, mx);               // row-uniform
        const float alpha = __builtin_amdgcn_exp2f(m_r - mnew);
        l_r *= alpha;
        #pragma unroll
        for (int d = 0; d < 4; ++d)
            #pragma unroll
            for (int r = 0; r < 4; ++r) accO[d][r] *= alpha;
        m_r = mnew;
    }

    // exp2 with (possibly stale-by-<=THR) m_r: values bounded by 2^THR = 256, f16-safe.
    #pragma unroll
    for (int sub = 0; sub < 4; ++sub)
        #pragma unroll
        for (int r = 0; r < 4; ++r)
            ps[sub][r] = __builtin_amdgcn_exp2f(ps[sub][r] - m_r);

    // P -> LDS relayout first (get ds_writes in flight early): row q=l15, col k
    #pragma unroll
    for (int sub = 0; sub < 4; ++sub) {
        f16x4 q4;
        q4[0] = (_Float16)ps[sub][0]; q4[1] = (_Float16)ps[sub][1];
        q4[2] = (_Float16)ps[sub][2]; q4[3] = (_Float16)ps[sub][3];
        *(f16x4*)&Plw[l15][sub * 16 + g * 4] = q4;
    }

    // per-lane partial row-sum; cross-lane reduce deferred to epilogue
    float rs = 0.f;
    #pragma unroll
    for (int sub = 0; sub < 4; ++sub)
        #pragma unroll
        for (int r = 0; r < 4; ++r) rs += ps[sub][r];
    l_r += rs;

    asm volatile("s_waitcnt lgkmcnt(0)" ::: "memory");
    __builtin_amdgcn_sched_barrier(0);

    f16x8 pb[2];
    pb[0] = *(const f16x8*)&Plw[l15][g * 8];
    pb[1] = *(const f16x8*)&Plw[l15][32 + g * 8];

    // PV swapped: A = V^T rows (d), B = P^T cols (q) -> accO[dsub]: d = dsub*16+g*4+r, q = l15
    __builtin_amdgcn_s_setprio(1);
    #pragma unroll
    for (int d = 0; d < 4; ++d)
        #pragma unroll
        for (int kc = 0; kc < 2; ++kc) {
            f16x8 av = *(const f16x8*)(Vb + ((d * 16 + l15) * 64 + (((kc * 4 + g) ^ sx) << 3)));
            accO[d] = __builtin_amdgcn_mfma_f32_16x16x32_f16(av, pb[kc], accO[d], 0, 0, 0);
        }
    __builtin_amdgcn_s_setprio(0);
}

__global__ __launch_bounds__(512, 4) void attn_main(
    const float* __restrict__ Q, const char* __restrict__ ws, float* __restrict__ O)
{
    __shared__ _Float16 SM[2][8192];        // [buf][ K tile 0..4095 | V tile 4096..8191 ]
    __shared__ _Float16 Pl[NW][16][72];

    const int tid  = threadIdx.x;
    const int lane = tid & 63;
    const int w    = tid >> 6;              // wave 0..7
    const int g    = lane >> 4;
    const int l15  = lane & 15;
    const int sx   = l15 & 7;

    // 1-D grid: id = bh + 32*qi  ->  id%8 = bh%8 (head -> XCD affinity, K/V L2-resident);
    // qt reversed so heaviest blocks dispatch first.
    const int id    = blockIdx.x;
    const int bh    = id & 31;
    const int qt    = (S_ / BQ - 1) - (id >> 5);
    const int qbase = qt * BQ;

    const char* kbase = ws + (size_t)bh * KBYTES_PER_HEAD;
    const char* vbase = ws + WS_V_OFF + (size_t)bh * KBYTES_PER_HEAD;

    // hoist Q fragments, pre-scaled into exp2 domain
    f16x8 aq[2];
    {
        const float* qrow = Q + ((size_t)bh * S_ + qbase + w * 16 + l15) * D_;
        #pragma unroll
        for (int kc = 0; kc < 2; ++kc) {
            const float4* p = (const float4*)(qrow + kc * 32 + g * 8);
            float4 x0 = p[0], x1 = p[1];
            f16x8 h;
            h[0] = (_Float16)(x0.x * QSCALE); h[1] = (_Float16)(x0.y * QSCALE);
            h[2] = (_Float16)(x0.z * QSCALE); h[3] = (_Float16)(x0.w * QSCALE);
            h[4] = (_Float16)(x1.x * QSCALE); h[5] = (_Float16)(x1.y * QSCALE);
            h[6] = (_Float16)(x1.z * QSCALE); h[7] = (_Float16)(x1.w * QSCALE);
            aq[kc] = h;
        }
    }

    f32x4 accO[4];
    #pragma unroll
    for (int i = 0; i < 4; ++i) accO[i] = (f32x4){0.f, 0.f, 0.f, 0.f};
    float m_r = -1e30f, l_r = 0.f;

    const int nt = 2 * qt + 2;              // tiles; last two straddle the diagonal
    const int dqw = qbase + w * 16;         // wave q-row base

    // stage tile t: 16 x 1KB chunks, 2 per wave, linear LDS dest (pre-swizzled source)
    auto STAGE = [&](int t, int buf) {
        #pragma unroll
        for (int i = 0; i < 2; ++i) {
            const int c = w * 2 + i;
            const char* src = (c < 8 ? kbase + (size_t)t * 8192 + c * 1024
                                     : vbase + (size_t)t * 8192 + (c - 8) * 1024) + lane * 16;
            __builtin_amdgcn_global_load_lds((gu32*)src, (lu32*)&SM[buf][c * 512], 16, 0, 0);
        }
    };

    STAGE(0, 0);
    for (int t = 0; t < nt - 2; ++t) {      // fully-visible tiles
        STAGE(t + 1, (t + 1) & 1);
        asm volatile("s_waitcnt vmcnt(2)" ::: "memory");
        __builtin_amdgcn_s_barrier();
        compute_tile<false>(&SM[t & 1][0], Pl[w], aq, accO, m_r, l_r, g, l15, sx, 0);
        __builtin_amdgcn_s_barrier();
    }
    // t = nt-2 (diagonal for waves 0-3)
    STAGE(nt - 1, (nt - 1) & 1);
    asm volatile("s_waitcnt vmcnt(2)" ::: "memory");
    __builtin_amdgcn_s_barrier();
    compute_tile<true>(&SM[(nt - 2) & 1][0], Pl[w], aq, accO, m_r, l_r, g, l15, sx,
                       dqw - (nt - 2) * 64);
    __builtin_amdgcn_s_barrier();
    // t = nt-1 (diagonal for waves 4-7; fully masked for 0-3)
    asm volatile("s_waitcnt vmcnt(0)" ::: "memory");
    __builtin_amdgcn_s_barrier();
    compute_tile<true>(&SM[(nt - 1) & 1][0], Pl[w], aq, accO, m_r, l_r, g, l15, sx,
                       dqw - (nt - 1) * 64);

    // epilogue: complete the deferred row-sum reduce (once per kernel, not per tile)
    float l = l_r;
    l += __shfl_xor(l, 16);
    l += __shfl_xor(l, 32);
    const float inv = 1.0f / l;
    float* orow = O + ((size_t)bh * S_ + qbase + w * 16 + l15) * D_;
    #pragma unroll
    for (int d = 0; d < 4; ++d) {
        f32x4 o = accO[d] * inv;
        *(f32x4*)&orow[d * 16 + g * 4] = o;
    }
}

extern "C" void kernel_launch(void* const* d_in, const int* in_sizes, int n_in,
                              void* d_out, int out_size, void* d_ws, size_t ws_size,
                              hipStream_t stream) {
    const float* q = (const float*)d_in[0];
    const float* k = (const float*)d_in[1];
    const float* v = (const float*)d_in[2];
    // d_in[3] (mask) intentionally never read — causality computed in-kernel
    float* o = (float*)d_out;
    char* ws = (char*)d_ws;

    if (ws_size < WS_NEED) return;

    const int kblocks = (B_ * H_ * S_ * 8) / 256;        // 1024
    const int vblocks = B_ * H_ * (S_ / 64);             // 1024
    prep_kv<<<kblocks + vblocks, 256, 0, stream>>>(k, v, ws);
    attn_main<<<(S_ / BQ) * B_ * H_, 512, 0, stream>>>(q, ws, o);
}

// Round 7
// 53.683 us; speedup vs baseline: 1.0008x; 1.0000x over previous
//
#include <hip/hip_runtime.h>

#define B_   2
#define H_   16
#define S_   2048
#define D_   64
#define BQ   128    // q rows per block (16 per wave, 8 waves)
#define BK   64
#define NW   8
// fold 1/sqrt(64) * log2(e) into Q so softmax works in exp2 domain
#define QSCALE 0.18033688011112042f
#define DEFER_THR 8.0f

typedef _Float16 f16x8 __attribute__((ext_vector_type(8)));
typedef _Float16 f16x4 __attribute__((ext_vector_type(4)));
typedef float    f32x4 __attribute__((ext_vector_type(4)));

typedef const unsigned int __attribute__((address_space(1))) gu32;
typedef unsigned int       __attribute__((address_space(3))) lu32;

#define KBYTES_PER_HEAD (S_ * 128)                       // 256 KB f16 per head per tensor
#define WS_V_OFF ((size_t)B_ * H_ * KBYTES_PER_HEAD)     // 8.4 MB
#define WS_NEED  (2 * WS_V_OFF)

// ---------------- fused prepass: K -> swizzled f16 tiles, V -> transposed swizzled f16 tiles
// K tile image: element (row,d) at byte  row*128 + (((d>>3) ^ (row&7))<<4) + (d&7)*2
// V tile image: element (d,k)  at byte  d*128   + (((k>>3) ^ (d&7))<<4)   + (k&7)*2
__global__ __launch_bounds__(256) void prep_kv(const float* __restrict__ K,
                                               const float* __restrict__ V,
                                               char* __restrict__ ws)
{
    if (blockIdx.x < (B_ * H_ * S_ * 8) / 256) {
        const int gidx = blockIdx.x * 256 + threadIdx.x;
        const int gcol = gidx & 7;
        const int srow = gidx >> 3;                      // bh*S + s
        const float4* src = (const float4*)(K + (size_t)srow * D_ + gcol * 8);
        float4 a = src[0], b = src[1];
        f16x8 h;
        h[0] = (_Float16)a.x; h[1] = (_Float16)a.y; h[2] = (_Float16)a.z; h[3] = (_Float16)a.w;
        h[4] = (_Float16)b.x; h[5] = (_Float16)b.y; h[6] = (_Float16)b.z; h[7] = (_Float16)b.w;
        const int s  = srow & (S_ - 1);
        const int bh = srow >> 11;
        size_t off = (size_t)bh * KBYTES_PER_HEAD + (size_t)(s >> 6) * 8192
                   + (s & 63) * 128 + ((gcol ^ (s & 7)) << 4);
        *(f16x8*)(ws + off) = h;
    } else {
        __shared__ _Float16 Vl[64][72];
        const int tile = blockIdx.x - (B_ * H_ * S_ * 8) / 256;  // bh*32 + t
        const int bh = tile >> 5, t = tile & 31;
        const float* vb = V + ((size_t)bh * S_ + t * 64) * D_;
        const int tid = threadIdx.x;
        #pragma unroll
        for (int it = 0; it < 2; ++it) {
            const int row = (tid >> 3) + it * 32;
            const int c8  = (tid & 7) * 8;
            const float4* p = (const float4*)(vb + row * D_ + c8);
            float4 a = p[0], b = p[1];
            f16x8 h;
            h[0] = (_Float16)a.x; h[1] = (_Float16)a.y; h[2] = (_Float16)a.z; h[3] = (_Float16)a.w;
            h[4] = (_Float16)b.x; h[5] = (_Float16)b.y; h[6] = (_Float16)b.z; h[7] = (_Float16)b.w;
            *(f16x8*)&Vl[row][c8] = h;
        }
        __syncthreads();
        char* out = ws + WS_V_OFF + (size_t)bh * KBYTES_PER_HEAD + t * 8192;
        #pragma unroll
        for (int it = 0; it < 2; ++it) {
            const int task = tid + it * 256;
            const int d = task >> 3, kg = task & 7;
            f16x8 h;
            #pragma unroll
            for (int j = 0; j < 8; ++j) h[j] = Vl[kg * 8 + j][d];
            *(f16x8*)(out + d * 128 + ((kg ^ (d & 7)) << 4)) = h;
        }
    }
}

// ---------------- main attention kernel
template<bool MASK>
__device__ __forceinline__ void compute_tile(
    const _Float16* __restrict__ SMb, _Float16 (*__restrict__ Plw)[72],
    const f16x8 aq[2], f32x4 accO[4], float& m_r, float& l_r,
    int g, int l15, int sx, int dq)
{
    const _Float16* Kb = SMb;
    const _Float16* Vb = SMb + 4096;

    // QK^T swapped: A = K rows, B = Q  ->  C[k = sub*16+g*4+r][q = l15]
    f32x4 accS[4];
    #pragma unroll
    for (int s = 0; s < 4; ++s) accS[s] = (f32x4){0.f, 0.f, 0.f, 0.f};
    __builtin_amdgcn_s_setprio(1);
    #pragma unroll
    for (int sub = 0; sub < 4; ++sub) {
        if (MASK && (sub * 16 > dq + 15)) continue;      // wave-uniform fully-masked sub
        #pragma unroll
        for (int kc = 0; kc < 2; ++kc) {
            f16x8 ak = *(const f16x8*)(Kb + ((sub * 16 + l15) * 64 + (((kc * 4 + g) ^ sx) << 3)));
            accS[sub] = __builtin_amdgcn_mfma_f32_16x16x32_f16(ak, aq[kc], accS[sub], 0, 0, 0);
        }
    }
    __builtin_amdgcn_s_setprio(0);

    // masked scores + per-lane local max (this lane's 16 k-values for q = l15)
    float ps[4][4];
    float pmax = -1e30f;
    #pragma unroll
    for (int sub = 0; sub < 4; ++sub) {
        const bool fullmask = MASK && (sub * 16 > dq + 15);
        const bool diag     = MASK && !fullmask && (sub * 16 + 15 > dq);
        #pragma unroll
        for (int r = 0; r < 4; ++r) {
            float s = fullmask ? -1e30f : accS[sub][r];
            if (diag && (sub * 16 + g * 4 + r > dq + l15)) s = -1e30f;
            ps[sub][r] = s;
            pmax = fmaxf(pmax, s);
        }
    }

    // defer-max (T13): rescale only when some lane's local max outgrows m_r + THR.
    // Branch is wave-uniform (ballot). Common case: no cross-lane ops at all.
    if (!__all(pmax <= m_r + DEFER_THR)) {
        float mx = pmax;
        mx = fmaxf(mx, __shfl_xor(mx, 16));
        mx = fmaxf(mx, __shfl_xor(mx, 32));
        const float mnew  = fmaxf(m_r, mx);               // row-uniform
        const float alpha = __builtin_amdgcn_exp2f(m_r - mnew);
        l_r *= alpha;
        #pragma unroll
        for (int d = 0; d < 4; ++d)
            #pragma unroll
            for (int r = 0; r < 4; ++r) accO[d][r] *= alpha;
        m_r = mnew;
    }

    // exp2 with (possibly stale-by-<=THR) m_r: values bounded by 2^THR = 256, f16-safe.
    #pragma unroll
    for (int sub = 0; sub < 4; ++sub)
        #pragma unroll
        for (int r = 0; r < 4; ++r)
            ps[sub][r] = __builtin_amdgcn_exp2f(ps[sub][r] - m_r);

    // P -> LDS relayout first (get ds_writes in flight early): row q=l15, col k
    #pragma unroll
    for (int sub = 0; sub < 4; ++sub) {
        f16x4 q4;
        q4[0] = (_Float16)ps[sub][0]; q4[1] = (_Float16)ps[sub][1];
        q4[2] = (_Float16)ps[sub][2]; q4[3] = (_Float16)ps[sub][3];
        *(f16x4*)&Plw[l15][sub * 16 + g * 4] = q4;
    }

    // per-lane partial row-sum; cross-lane reduce deferred to epilogue
    float rs = 0.f;
    #pragma unroll
    for (int sub = 0; sub < 4; ++sub)
        #pragma unroll
        for (int r = 0; r < 4; ++r) rs += ps[sub][r];
    l_r += rs;

    asm volatile("s_waitcnt lgkmcnt(0)" ::: "memory");
    __builtin_amdgcn_sched_barrier(0);

    f16x8 pb[2];
    pb[0] = *(const f16x8*)&Plw[l15][g * 8];
    pb[1] = *(const f16x8*)&Plw[l15][32 + g * 8];

    // PV swapped: A = V^T rows (d), B = P^T cols (q) -> accO[dsub]: d = dsub*16+g*4+r, q = l15
    __builtin_amdgcn_s_setprio(1);
    #pragma unroll
    for (int d = 0; d < 4; ++d)
        #pragma unroll
        for (int kc = 0; kc < 2; ++kc) {
            f16x8 av = *(const f16x8*)(Vb + ((d * 16 + l15) * 64 + (((kc * 4 + g) ^ sx) << 3)));
            accO[d] = __builtin_amdgcn_mfma_f32_16x16x32_f16(av, pb[kc], accO[d], 0, 0, 0);
        }
    __builtin_amdgcn_s_setprio(0);
}

__global__ __launch_bounds__(512, 4) void attn_main(
    const float* __restrict__ Q, const char* __restrict__ ws, float* __restrict__ O)
{
    __shared__ _Float16 SM[2][8192];        // [buf][ K tile 0..4095 | V tile 4096..8191 ]
    __shared__ _Float16 Pl[NW][16][72];

    const int tid  = threadIdx.x;
    const int lane = tid & 63;
    const int w    = tid >> 6;              // wave 0..7
    const int g    = lane >> 4;
    const int l15  = lane & 15;
    const int sx   = l15 & 7;

    // 1-D grid: id = bh + 32*qi  ->  id%8 = bh%8 (head -> XCD affinity, K/V L2-resident);
    // qt reversed so heaviest blocks dispatch first.
    const int id    = blockIdx.x;
    const int bh    = id & 31;
    const int qt    = (S_ / BQ - 1) - (id >> 5);
    const int qbase = qt * BQ;

    const char* kbase = ws + (size_t)bh * KBYTES_PER_HEAD;
    const char* vbase = ws + WS_V_OFF + (size_t)bh * KBYTES_PER_HEAD;

    // hoist Q fragments, pre-scaled into exp2 domain
    f16x8 aq[2];
    {
        const float* qrow = Q + ((size_t)bh * S_ + qbase + w * 16 + l15) * D_;
        #pragma unroll
        for (int kc = 0; kc < 2; ++kc) {
            const float4* p = (const float4*)(qrow + kc * 32 + g * 8);
            float4 x0 = p[0], x1 = p[1];
            f16x8 h;
            h[0] = (_Float16)(x0.x * QSCALE); h[1] = (_Float16)(x0.y * QSCALE);
            h[2] = (_Float16)(x0.z * QSCALE); h[3] = (_Float16)(x0.w * QSCALE);
            h[4] = (_Float16)(x1.x * QSCALE); h[5] = (_Float16)(x1.y * QSCALE);
            h[6] = (_Float16)(x1.z * QSCALE); h[7] = (_Float16)(x1.w * QSCALE);
            aq[kc] = h;
        }
    }

    f32x4 accO[4];
    #pragma unroll
    for (int i = 0; i < 4; ++i) accO[i] = (f32x4){0.f, 0.f, 0.f, 0.f};
    float m_r = -1e30f, l_r = 0.f;

    const int nt = 2 * qt + 2;              // tiles; last two straddle the diagonal
    const int dqw = qbase + w * 16;         // wave q-row base

    // stage tile t: 16 x 1KB chunks, 2 per wave, linear LDS dest (pre-swizzled source)
    auto STAGE = [&](int t, int buf) {
        #pragma unroll
        for (int i = 0; i < 2; ++i) {
            const int c = w * 2 + i;
            const char* src = (c < 8 ? kbase + (size_t)t * 8192 + c * 1024
                                     : vbase + (size_t)t * 8192 + (c - 8) * 1024) + lane * 16;
            __builtin_amdgcn_global_load_lds((gu32*)src, (lu32*)&SM[buf][c * 512], 16, 0, 0);
        }
    };

    STAGE(0, 0);
    for (int t = 0; t < nt - 2; ++t) {      // fully-visible tiles
        STAGE(t + 1, (t + 1) & 1);
        asm volatile("s_waitcnt vmcnt(2)" ::: "memory");
        __builtin_amdgcn_s_barrier();
        compute_tile<false>(&SM[t & 1][0], Pl[w], aq, accO, m_r, l_r, g, l15, sx, 0);
        __builtin_amdgcn_s_barrier();
    }
    // t = nt-2 (diagonal for waves 0-3)
    STAGE(nt - 1, (nt - 1) & 1);
    asm volatile("s_waitcnt vmcnt(2)" ::: "memory");
    __builtin_amdgcn_s_barrier();
    compute_tile<true>(&SM[(nt - 2) & 1][0], Pl[w], aq, accO, m_r, l_r, g, l15, sx,
                       dqw - (nt - 2) * 64);
    __builtin_amdgcn_s_barrier();
    // t = nt-1 (diagonal for waves 4-7; fully masked for 0-3)
    asm volatile("s_waitcnt vmcnt(0)" ::: "memory");
    __builtin_amdgcn_s_barrier();
    compute_tile<true>(&SM[(nt - 1) & 1][0], Pl[w], aq, accO, m_r, l_r, g, l15, sx,
                       dqw - (nt - 1) * 64);

    // epilogue: complete the deferred row-sum reduce (once per kernel, not per tile)
    float l = l_r;
    l += __shfl_xor(l, 16);
    l += __shfl_xor(l, 32);
    const float inv = 1.0f / l;
    float* orow = O + ((size_t)bh * S_ + qbase + w * 16 + l15) * D_;
    #pragma unroll
    for (int d = 0; d < 4; ++d) {
        f32x4 o = accO[d] * inv;
        *(f32x4*)&orow[d * 16 + g * 4] = o;
    }
}

extern "C" void kernel_launch(void* const* d_in, const int* in_sizes, int n_in,
                              void* d_out, int out_size, void* d_ws, size_t ws_size,
                              hipStream_t stream) {
    const float* q = (const float*)d_in[0];
    const float* k = (const float*)d_in[1];
    const float* v = (const float*)d_in[2];
    // d_in[3] (mask) intentionally never read — causality computed in-kernel
    float* o = (float*)d_out;
    char* ws = (char*)d_ws;

    if (ws_size < WS_NEED) return;

    const int kblocks = (B_ * H_ * S_ * 8) / 256;        // 1024
    const int vblocks = B_ * H_ * (S_ / 64);             // 1024
    prep_kv<<<kblocks + vblocks, 256, 0, stream>>>(k, v, ws);
    attn_main<<<(S_ / BQ) * B_ * H_, 512, 0, stream>>>(q, ws, o);
}

// Round 8
// 53.523 us; speedup vs baseline: 1.0038x; 1.0030x over previous
//
#include <hip/hip_runtime.h>

#define B_   2
#define H_   16
#define S_   2048
#define D_   64
#define BQ   128    // q rows per block (16 per wave, 8 waves)
#define BK   64
#define NW   8
// fold 1/sqrt(64) * log2(e) into Q so softmax works in exp2 domain
#define QSCALE 0.18033688011112042f
#define DEFER_THR 8.0f

typedef _Float16 f16x8 __attribute__((ext_vector_type(8)));
typedef _Float16 f16x4 __attribute__((ext_vector_type(4)));
typedef float    f32x4 __attribute__((ext_vector_type(4)));

typedef const unsigned int __attribute__((address_space(1))) gu32;
typedef unsigned int       __attribute__((address_space(3))) lu32;

#define KBYTES_PER_HEAD (S_ * 128)                       // 256 KB f16 per head per tensor
#define WS_V_OFF ((size_t)B_ * H_ * KBYTES_PER_HEAD)     // 8.4 MB
#define WS_NEED  (2 * WS_V_OFF)

// ---------------- fused prepass: K -> swizzled f16 tiles, V -> transposed swizzled f16 tiles
// K tile image: element (row,d) at byte  row*128 + (((d>>3) ^ (row&7))<<4) + (d&7)*2
// V tile image: element (d,k)  at byte  d*128   + (((k>>3) ^ (d&7))<<4)   + (k&7)*2
__global__ __launch_bounds__(256) void prep_kv(const float* __restrict__ K,
                                               const float* __restrict__ V,
                                               char* __restrict__ ws)
{
    if (blockIdx.x < (B_ * H_ * S_ * 8) / 256) {
        const int gidx = blockIdx.x * 256 + threadIdx.x;
        const int gcol = gidx & 7;
        const int srow = gidx >> 3;                      // bh*S + s
        const float4* src = (const float4*)(K + (size_t)srow * D_ + gcol * 8);
        float4 a = src[0], b = src[1];
        f16x8 h;
        h[0] = (_Float16)a.x; h[1] = (_Float16)a.y; h[2] = (_Float16)a.z; h[3] = (_Float16)a.w;
        h[4] = (_Float16)b.x; h[5] = (_Float16)b.y; h[6] = (_Float16)b.z; h[7] = (_Float16)b.w;
        const int s  = srow & (S_ - 1);
        const int bh = srow >> 11;
        size_t off = (size_t)bh * KBYTES_PER_HEAD + (size_t)(s >> 6) * 8192
                   + (s & 63) * 128 + ((gcol ^ (s & 7)) << 4);
        *(f16x8*)(ws + off) = h;
    } else {
        __shared__ _Float16 Vl[64][72];
        const int tile = blockIdx.x - (B_ * H_ * S_ * 8) / 256;  // bh*32 + t
        const int bh = tile >> 5, t = tile & 31;
        const float* vb = V + ((size_t)bh * S_ + t * 64) * D_;
        const int tid = threadIdx.x;
        #pragma unroll
        for (int it = 0; it < 2; ++it) {
            const int row = (tid >> 3) + it * 32;
            const int c8  = (tid & 7) * 8;
            const float4* p = (const float4*)(vb + row * D_ + c8);
            float4 a = p[0], b = p[1];
            f16x8 h;
            h[0] = (_Float16)a.x; h[1] = (_Float16)a.y; h[2] = (_Float16)a.z; h[3] = (_Float16)a.w;
            h[4] = (_Float16)b.x; h[5] = (_Float16)b.y; h[6] = (_Float16)b.z; h[7] = (_Float16)b.w;
            *(f16x8*)&Vl[row][c8] = h;
        }
        __syncthreads();
        char* out = ws + WS_V_OFF + (size_t)bh * KBYTES_PER_HEAD + t * 8192;
        #pragma unroll
        for (int it = 0; it < 2; ++it) {
            const int task = tid + it * 256;
            const int d = task >> 3, kg = task & 7;
            f16x8 h;
            #pragma unroll
            for (int j = 0; j < 8; ++j) h[j] = Vl[kg * 8 + j][d];
            *(f16x8*)(out + d * 128 + ((kg ^ (d & 7)) << 4)) = h;
        }
    }
}

// ---------------- main attention kernel
template<bool MASK>
__device__ __forceinline__ void compute_tile(
    const _Float16* __restrict__ SMb, _Float16 (*__restrict__ Plw)[72],
    const f16x8 aq[2], f32x4 accO[4], float& m_r, float& l_r,
    int g, int l15, int sx, int dq)
{
    const _Float16* Kb = SMb;
    const _Float16* Vb = SMb + 4096;

    // QK^T swapped: A = K rows, B = Q  ->  C[k = sub*16+g*4+r][q = l15]
    f32x4 accS[4];
    #pragma unroll
    for (int s = 0; s < 4; ++s) accS[s] = (f32x4){0.f, 0.f, 0.f, 0.f};
    __builtin_amdgcn_s_setprio(1);
    #pragma unroll
    for (int sub = 0; sub < 4; ++sub) {
        if (MASK && (sub * 16 > dq + 15)) continue;      // wave-uniform fully-masked sub
        #pragma unroll
        for (int kc = 0; kc < 2; ++kc) {
            f16x8 ak = *(const f16x8*)(Kb + ((sub * 16 + l15) * 64 + (((kc * 4 + g) ^ sx) << 3)));
            accS[sub] = __builtin_amdgcn_mfma_f32_16x16x32_f16(ak, aq[kc], accS[sub], 0, 0, 0);
        }
    }
    __builtin_amdgcn_s_setprio(0);

    // masked scores + per-lane local max (this lane's 16 k-values for q = l15)
    float ps[4][4];
    float pmax = -1e30f;
    #pragma unroll
    for (int sub = 0; sub < 4; ++sub) {
        const bool fullmask = MASK && (sub * 16 > dq + 15);
        const bool diag     = MASK && !fullmask && (sub * 16 + 15 > dq);
        #pragma unroll
        for (int r = 0; r < 4; ++r) {
            float s = fullmask ? -1e30f : accS[sub][r];
            if (diag && (sub * 16 + g * 4 + r > dq + l15)) s = -1e30f;
            ps[sub][r] = s;
            pmax = fmaxf(pmax, s);
        }
    }

    // defer-max (T13): rescale only when some lane's local max outgrows m_r + THR.
    // Branch is wave-uniform (ballot). Common case: no cross-lane ops at all.
    if (!__all(pmax <= m_r + DEFER_THR)) {
        float mx = pmax;
        mx = fmaxf(mx, __shfl_xor(mx, 16));
        mx = fmaxf(mx, __shfl_xor(mx, 32));
        const float mnew  = fmaxf(m_r, mx);               // row-uniform
        const float alpha = __builtin_amdgcn_exp2f(m_r - mnew);
        l_r *= alpha;
        #pragma unroll
        for (int d = 0; d < 4; ++d)
            #pragma unroll
            for (int r = 0; r < 4; ++r) accO[d][r] *= alpha;
        m_r = mnew;
    }

    // exp2 with (possibly stale-by-<=THR) m_r: values bounded by 2^THR = 256, f16-safe.
    #pragma unroll
    for (int sub = 0; sub < 4; ++sub)
        #pragma unroll
        for (int r = 0; r < 4; ++r)
            ps[sub][r] = __builtin_amdgcn_exp2f(ps[sub][r] - m_r);

    // P -> LDS relayout first (get ds_writes in flight early): row q=l15, col k
    #pragma unroll
    for (int sub = 0; sub < 4; ++sub) {
        f16x4 q4;
        q4[0] = (_Float16)ps[sub][0]; q4[1] = (_Float16)ps[sub][1];
        q4[2] = (_Float16)ps[sub][2]; q4[3] = (_Float16)ps[sub][3];
        *(f16x4*)&Plw[l15][sub * 16 + g * 4] = q4;
    }

    // per-lane partial row-sum; cross-lane reduce deferred to epilogue
    float rs = 0.f;
    #pragma unroll
    for (int sub = 0; sub < 4; ++sub)
        #pragma unroll
        for (int r = 0; r < 4; ++r) rs += ps[sub][r];
    l_r += rs;

    asm volatile("s_waitcnt lgkmcnt(0)" ::: "memory");
    __builtin_amdgcn_sched_barrier(0);

    f16x8 pb[2];
    pb[0] = *(const f16x8*)&Plw[l15][g * 8];
    pb[1] = *(const f16x8*)&Plw[l15][32 + g * 8];

    // PV swapped: A = V^T rows (d), B = P^T cols (q) -> accO[dsub]: d = dsub*16+g*4+r, q = l15
    __builtin_amdgcn_s_setprio(1);
    #pragma unroll
    for (int d = 0; d < 4; ++d)
        #pragma unroll
        for (int kc = 0; kc < 2; ++kc) {
            f16x8 av = *(const f16x8*)(Vb + ((d * 16 + l15) * 64 + (((kc * 4 + g) ^ sx) << 3)));
            accO[d] = __builtin_amdgcn_mfma_f32_16x16x32_f16(av, pb[kc], accO[d], 0, 0, 0);
        }
    __builtin_amdgcn_s_setprio(0);
}

__global__ __launch_bounds__(512, 4) void attn_main(
    const float* __restrict__ Q, const char* __restrict__ ws, float* __restrict__ O)
{
    __shared__ _Float16 SM[2][8192];        // [buf][ K tile 0..4095 | V tile 4096..8191 ]
    __shared__ _Float16 Pl[NW][16][72];

    const int tid  = threadIdx.x;
    const int lane = tid & 63;
    const int w    = tid >> 6;              // wave 0..7
    const int g    = lane >> 4;
    const int l15  = lane & 15;
    const int sx   = l15 & 7;

    // Balanced pairing: blocks i and i+256 co-reside on the same CU
    // (same XCD i%8, same CU slot (i>>3)%32). Map id<256 -> heavy strips
    // (qt 15..8, dispatched first), id>=256 -> light strips (qt 0..7), so
    // every CU's pair totals exactly (2(15-qi)+2)+(2qi+2) = 36 tile-units.
    // bh = id&31 keeps head->XCD L2 affinity for both halves (256%8==0).
    const int id    = blockIdx.x;
    const int bh    = id & 31;
    const int qi    = id >> 5;              // 0..15
    const int qt    = (id < 256) ? (15 - qi) : (qi - 8);
    const int qbase = qt * BQ;

    const char* kbase = ws + (size_t)bh * KBYTES_PER_HEAD;
    const char* vbase = ws + WS_V_OFF + (size_t)bh * KBYTES_PER_HEAD;

    // hoist Q fragments, pre-scaled into exp2 domain
    f16x8 aq[2];
    {
        const float* qrow = Q + ((size_t)bh * S_ + qbase + w * 16 + l15) * D_;
        #pragma unroll
        for (int kc = 0; kc < 2; ++kc) {
            const float4* p = (const float4*)(qrow + kc * 32 + g * 8);
            float4 x0 = p[0], x1 = p[1];
            f16x8 h;
            h[0] = (_Float16)(x0.x * QSCALE); h[1] = (_Float16)(x0.y * QSCALE);
            h[2] = (_Float16)(x0.z * QSCALE); h[3] = (_Float16)(x0.w * QSCALE);
            h[4] = (_Float16)(x1.x * QSCALE); h[5] = (_Float16)(x1.y * QSCALE);
            h[6] = (_Float16)(x1.z * QSCALE); h[7] = (_Float16)(x1.w * QSCALE);
            aq[kc] = h;
        }
    }

    f32x4 accO[4];
    #pragma unroll
    for (int i = 0; i < 4; ++i) accO[i] = (f32x4){0.f, 0.f, 0.f, 0.f};
    float m_r = -1e30f, l_r = 0.f;

    const int nt = 2 * qt + 2;              // tiles; last two straddle the diagonal
    const int dqw = qbase + w * 16;         // wave q-row base

    // stage tile t: 16 x 1KB chunks, 2 per wave, linear LDS dest (pre-swizzled source)
    auto STAGE = [&](int t, int buf) {
        #pragma unroll
        for (int i = 0; i < 2; ++i) {
            const int c = w * 2 + i;
            const char* src = (c < 8 ? kbase + (size_t)t * 8192 + c * 1024
                                     : vbase + (size_t)t * 8192 + (c - 8) * 1024) + lane * 16;
            __builtin_amdgcn_global_load_lds((gu32*)src, (lu32*)&SM[buf][c * 512], 16, 0, 0);
        }
    };

    STAGE(0, 0);
    for (int t = 0; t < nt - 2; ++t) {      // fully-visible tiles
        STAGE(t + 1, (t + 1) & 1);
        asm volatile("s_waitcnt vmcnt(2)" ::: "memory");
        __builtin_amdgcn_s_barrier();
        compute_tile<false>(&SM[t & 1][0], Pl[w], aq, accO, m_r, l_r, g, l15, sx, 0);
        __builtin_amdgcn_s_barrier();
    }
    // t = nt-2 (diagonal for waves 0-3)
    STAGE(nt - 1, (nt - 1) & 1);
    asm volatile("s_waitcnt vmcnt(2)" ::: "memory");
    __builtin_amdgcn_s_barrier();
    compute_tile<true>(&SM[(nt - 2) & 1][0], Pl[w], aq, accO, m_r, l_r, g, l15, sx,
                       dqw - (nt - 2) * 64);
    __builtin_amdgcn_s_barrier();
    // t = nt-1 (diagonal for waves 4-7; fully masked for 0-3)
    asm volatile("s_waitcnt vmcnt(0)" ::: "memory");
    __builtin_amdgcn_s_barrier();
    compute_tile<true>(&SM[(nt - 1) & 1][0], Pl[w], aq, accO, m_r, l_r, g, l15, sx,
                       dqw - (nt - 1) * 64);

    // epilogue: complete the deferred row-sum reduce (once per kernel, not per tile)
    float l = l_r;
    l += __shfl_xor(l, 16);
    l += __shfl_xor(l, 32);
    const float inv = 1.0f / l;
    float* orow = O + ((size_t)bh * S_ + qbase + w * 16 + l15) * D_;
    #pragma unroll
    for (int d = 0; d < 4; ++d) {
        f32x4 o = accO[d] * inv;
        *(f32x4*)&orow[d * 16 + g * 4] = o;
    }
}

extern "C" void kernel_launch(void* const* d_in, const int* in_sizes, int n_in,
                              void* d_out, int out_size, void* d_ws, size_t ws_size,
                              hipStream_t stream) {
    const float* q = (const float*)d_in[0];
    const float* k = (const float*)d_in[1];
    const float* v = (const float*)d_in[2];
    // d_in[3] (mask) intentionally never read — causality computed in-kernel
    float* o = (float*)d_out;
    char* ws = (char*)d_ws;

    if (ws_size < WS_NEED) return;

    const int kblocks = (B_ * H_ * S_ * 8) / 256;        // 1024
    const int vblocks = B_ * H_ * (S_ / 64);             // 1024
    prep_kv<<<kblocks + vblocks, 256, 0, stream>>>(k, v, ws);
    attn_main<<<(S_ / BQ) * B_ * H_, 512, 0, stream>>>(q, ws, o);
}